// Round 2
// baseline (461.674 us; speedup 1.0000x reference)
//
#include <hip/hip_runtime.h>

#define BATCH 4
#define N_PER 300
#define IN_DIM 256
#define KEY_DIM 32
#define FH 160
#define FW 160
#define HW (FH * FW)                 // 25600
#define NQ (BATCH * N_PER)           // 1200
#define Q_ELEMS (NQ * KEY_DIM)       // 38400 fp32 in ws: qry_feats [n][c]
#define KWT_ELEMS (IN_DIM * KEY_DIM) // 8192 fp32 in ws: key_w transposed [c][o]

#define QBLOCKS NQ                   // 1200 blocks: one per query row
#define TBLOCKS (KWT_ELEMS / 256)    // 32 transpose blocks
#define NHALF (N_PER / 2)            // 150 queries per thread-group in main
#define CHALF (IN_DIM / 2)           // 128 channels per thread-group

// ---------------------------------------------------------------------------
// Prep (unchanged from last round — correct and cheap):
// Blocks [0,1200): block n computes qry_feats[n][0..32) via float4 dot +
// 3x shfl_xor k-reduce.  Blocks [1200,1232): transpose key_w -> kwT[c][o].
// ---------------------------------------------------------------------------
__global__ __launch_bounds__(256) void prep_kernel(
        const float* __restrict__ in_feats,
        const float* __restrict__ qry_w,
        const float* __restrict__ qry_b,
        const float* __restrict__ key_w,
        float* __restrict__ ws) {
    const int bid = blockIdx.x;
    const int t = threadIdx.x;
    if (bid < QBLOCKS) {
        const int n   = bid;
        const int c   = t >> 3;      // 0..31
        const int sub = t & 7;       // 0..7  (k-chunk)
        const float4* __restrict__ f4 =
            (const float4*)(in_feats + n * IN_DIM + sub * 32);
        const float4* __restrict__ w4 =
            (const float4*)(qry_w + c * IN_DIM + sub * 32);
        float a0 = 0.f, a1 = 0.f, a2 = 0.f, a3 = 0.f;
        #pragma unroll
        for (int j = 0; j < 8; ++j) {
            float4 fv = f4[j];
            float4 wv = w4[j];
            a0 += fv.x * wv.x;
            a1 += fv.y * wv.y;
            a2 += fv.z * wv.z;
            a3 += fv.w * wv.w;
        }
        float s = (a0 + a1) + (a2 + a3);
        s += __shfl_xor(s, 1);
        s += __shfl_xor(s, 2);
        s += __shfl_xor(s, 4);
        if (sub == 0) ws[n * KEY_DIM + c] = s + qry_b[c];
    } else {
        const int i = (bid - QBLOCKS) * 256 + t;   // 0..8191
        const int c = i >> 5;                      // 0..255
        const int o = i & 31;                      // 0..31
        ws[Q_ELEMS + i] = key_w[o * IN_DIM + c];   // kwT[c*32 + o]
    }
}

// ---------------------------------------------------------------------------
// Fused main v3: 512 threads = 256 pixels x 2 channel-groups.
//   Phase 1: group g accumulates key[32] over channels [g*128, g*128+128)
//            (feat_map read coalesced, exactly once per element).
//   Exchange: g1 writes acc to LDS; g0 combines (+bias) and writes key back;
//            g1 reads key.  Only ONE 32-float array live per phase -> no
//            register squeeze (v2's 1024-thread/launch_bounds variant spilled:
//            VGPR capped at 64, WRITE_SIZE doubled, VALUBusy halved).
//   Phase 2: group g handles 150 queries for its pixel, same store pattern
//            as the proven 125 us v1 kernel (coalesced 256B/wave).
// No launch_bounds occupancy forcing; 32 KB LDS; grid 800 blocks = 6400 waves.
// ---------------------------------------------------------------------------
__global__ __launch_bounds__(512) void main_kernel(
        const float* __restrict__ feat_map,
        const float* __restrict__ key_b,
        const float* __restrict__ ws,
        float* __restrict__ out) {
    __shared__ float buf[KEY_DIM][256];            // 32 KB, [o][p]: 2-way free

    const int t   = threadIdx.x;
    const int p   = t & 255;                       // pixel within tile
    const int g   = t >> 8;                        // 0..1 (wave-uniform)
    const int b   = blockIdx.y;
    const int pix = blockIdx.x * 256 + p;

    const float* __restrict__ fb  =
        feat_map + ((size_t)b * IN_DIM + g * CHALF) * HW + pix;
    const float* __restrict__ kwT = ws + Q_ELEMS + (g * CHALF) * KEY_DIM;

    float acc[KEY_DIM];
    #pragma unroll
    for (int o = 0; o < KEY_DIM; ++o) acc[o] = 0.f;

    // Phase 1: 128 coalesced feat loads, 128x32 FMA into 32 indep chains.
    #pragma unroll 8
    for (int c = 0; c < CHALF; ++c) {
        float f = fb[(size_t)c * HW];
        const float* __restrict__ kr = kwT + c * KEY_DIM;
        #pragma unroll
        for (int o = 0; o < KEY_DIM; ++o) acc[o] += kr[o] * f;
    }

    // Cross-group exchange through one 32 KB LDS buffer (wave-uniform branches).
    if (g == 1) {
        #pragma unroll
        for (int o = 0; o < KEY_DIM; ++o) buf[o][p] = acc[o];
    }
    __syncthreads();
    float key[KEY_DIM];
    if (g == 0) {
        #pragma unroll
        for (int o = 0; o < KEY_DIM; ++o) {
            key[o] = acc[o] + buf[o][p] + key_b[o];
            buf[o][p] = key[o];
        }
    }
    __syncthreads();
    if (g == 1) {
        #pragma unroll
        for (int o = 0; o < KEY_DIM; ++o) key[o] = buf[o][p];
    }

    // Phase 2: 150 dot-32s per thread against wave-uniform q rows.
    const float* __restrict__ qb =
        ws + ((size_t)b * N_PER + g * NHALF) * KEY_DIM;
    float* __restrict__ ob =
        out + ((size_t)b * N_PER + (size_t)g * NHALF) * HW + pix;

    for (int n = 0; n < NHALF; ++n) {
        const float* __restrict__ qn = qb + n * KEY_DIM;
        float a0 = 0.f, a1 = 0.f, a2 = 0.f, a3 = 0.f;
        #pragma unroll
        for (int c2 = 0; c2 < KEY_DIM; c2 += 4) {
            a0 += qn[c2 + 0] * key[c2 + 0];
            a1 += qn[c2 + 1] * key[c2 + 1];
            a2 += qn[c2 + 2] * key[c2 + 2];
            a3 += qn[c2 + 3] * key[c2 + 3];
        }
        ob[(size_t)n * HW] = (a0 + a1) + (a2 + a3);
    }
}

extern "C" void kernel_launch(void* const* d_in, const int* in_sizes, int n_in,
                              void* d_out, int out_size, void* d_ws, size_t ws_size,
                              hipStream_t stream) {
    const float* in_feats = (const float*)d_in[0];  // [1200, 256]
    const float* feat_map = (const float*)d_in[1];  // [4, 256, 160, 160]
    const float* qry_w    = (const float*)d_in[2];  // [32, 256]
    const float* qry_b    = (const float*)d_in[3];  // [32]
    const float* key_w    = (const float*)d_in[4];  // [32, 256]
    const float* key_b    = (const float*)d_in[5];  // [32]
    float* ws  = (float*)d_ws;                      // needs 46592*4 B
    float* out = (float*)d_out;                     // [1200, 160, 160] fp32

    // Prep: 1200 q-blocks + 32 transpose blocks.
    prep_kernel<<<dim3(QBLOCKS + TBLOCKS), dim3(256), 0, stream>>>(
        in_feats, qry_w, qry_b, key_w, ws);

    // Main: 100 pixel-tiles x 4 batches, 512 threads each (6400 waves).
    main_kernel<<<dim3(HW / 256, BATCH), dim3(512), 0, stream>>>(
        feat_map, key_b, ws, out);
}

// Round 3
// 258.460 us; speedup vs baseline: 1.7863x; 1.7863x over previous
//
#include <hip/hip_runtime.h>

#define BATCH 4
#define N_PER 300
#define IN_DIM 256
#define KEY_DIM 32
#define FH 160
#define FW 160
#define HW (FH * FW)                 // 25600
#define NQ (BATCH * N_PER)           // 1200
#define Q_ELEMS (NQ * KEY_DIM)       // 38400 fp32 in ws: qry_feats [n][c]
#define KWT_ELEMS (IN_DIM * KEY_DIM) // 8192 fp32 in ws: key_w transposed [c][o]

#define QBLOCKS NQ                   // 1200 blocks: one per query row
#define TBLOCKS (KWT_ELEMS / 256)    // 32 transpose blocks
#define NHALF (N_PER / 2)            // 150 queries per thread-group in main
#define CHALF (IN_DIM / 2)           // 128 channels per thread-group

// ---------------------------------------------------------------------------
// Prep (unchanged — fast since round 1):
// Blocks [0,1200): block n computes qry_feats[n][0..32) via float4 dot +
// 3x shfl_xor k-reduce.  Blocks [1200,1232): transpose key_w -> kwT[c][o].
// ---------------------------------------------------------------------------
__global__ __launch_bounds__(256) void prep_kernel(
        const float* __restrict__ in_feats,
        const float* __restrict__ qry_w,
        const float* __restrict__ qry_b,
        const float* __restrict__ key_w,
        float* __restrict__ ws) {
    const int bid = blockIdx.x;
    const int t = threadIdx.x;
    if (bid < QBLOCKS) {
        const int n   = bid;
        const int c   = t >> 3;      // 0..31
        const int sub = t & 7;       // 0..7  (k-chunk)
        const float4* __restrict__ f4 =
            (const float4*)(in_feats + n * IN_DIM + sub * 32);
        const float4* __restrict__ w4 =
            (const float4*)(qry_w + c * IN_DIM + sub * 32);
        float a0 = 0.f, a1 = 0.f, a2 = 0.f, a3 = 0.f;
        #pragma unroll
        for (int j = 0; j < 8; ++j) {
            float4 fv = f4[j];
            float4 wv = w4[j];
            a0 += fv.x * wv.x;
            a1 += fv.y * wv.y;
            a2 += fv.z * wv.z;
            a3 += fv.w * wv.w;
        }
        float s = (a0 + a1) + (a2 + a3);
        s += __shfl_xor(s, 1);
        s += __shfl_xor(s, 2);
        s += __shfl_xor(s, 4);
        if (sub == 0) ws[n * KEY_DIM + c] = s + qry_b[c];
    } else {
        const int i = (bid - QBLOCKS) * 256 + t;   // 0..8191
        const int c = i >> 5;                      // 0..255
        const int o = i & 31;                      // 0..31
        ws[Q_ELEMS + i] = key_w[o * IN_DIM + c];   // kwT[c*32 + o]
    }
}

// ---------------------------------------------------------------------------
// Fused main v4: 512 threads = 256 pixels x 2 channel-groups, with the group
// index forced into an SGPR via readfirstlane BEFORE any pointer math.
//
// v3 post-mortem: g = threadIdx.x>>8 in pointer math defeated LLVM's
// uniformity analysis -> kwT/q loads became per-lane global_load broadcasts
// instead of s_loads -> 2x VALU issue + vmcnt stalls (VALUBusy*dur doubled
// vs v1).  readfirstlane(g) lives in an SGPR by construction, so all weight
// and query loads scalarize exactly as in the 125us v1 kernel, but with 2x
// the waves and no redundant compute.
//
// Phase 2 n-loop: unroll 2 so the compiler pipelines the next q-row's
// s_load (128 B, ~200cy latency) under the current row's 64cy of FMAs —
// v1's per-wave VALU duty was ~16% and this serial s_load was the stall.
// ---------------------------------------------------------------------------
__global__ __launch_bounds__(512) void main_kernel(
        const float* __restrict__ feat_map,
        const float* __restrict__ key_b,
        const float* __restrict__ ws,
        float* __restrict__ out) {
    __shared__ float buf[KEY_DIM][256];            // 32 KB, [o][p]: conflict-free

    const int t   = threadIdx.x;
    const int p   = t & 255;                       // pixel within tile
    const int g   = __builtin_amdgcn_readfirstlane(t >> 8);  // 0..1, SGPR
    const int b   = blockIdx.y;
    const int pix = blockIdx.x * 256 + p;

    const float* __restrict__ fb  =
        feat_map + ((size_t)b * IN_DIM + g * CHALF) * HW + pix;
    const float* __restrict__ kwT = ws + Q_ELEMS + (g * CHALF) * KEY_DIM;

    float acc[KEY_DIM];
    #pragma unroll
    for (int o = 0; o < KEY_DIM; ++o) acc[o] = 0.f;

    // Phase 1: 128 coalesced feat loads, 128x32 FMA into 32 indep chains.
    // kwT rows are scalar (s_load) — base is SGPR, index c is loop-uniform.
    #pragma unroll 8
    for (int c = 0; c < CHALF; ++c) {
        float f = fb[(size_t)c * HW];
        const float* __restrict__ kr = kwT + c * KEY_DIM;
        #pragma unroll
        for (int o = 0; o < KEY_DIM; ++o) acc[o] += kr[o] * f;
    }

    // Cross-group exchange through one 32 KB LDS buffer (uniform branches).
    if (g == 1) {
        #pragma unroll
        for (int o = 0; o < KEY_DIM; ++o) buf[o][p] = acc[o];
    }
    __syncthreads();
    float key[KEY_DIM];
    if (g == 0) {
        #pragma unroll
        for (int o = 0; o < KEY_DIM; ++o) {
            key[o] = acc[o] + buf[o][p] + key_b[o];
            buf[o][p] = key[o];
        }
    }
    __syncthreads();
    if (g == 1) {
        #pragma unroll
        for (int o = 0; o < KEY_DIM; ++o) key[o] = buf[o][p];
    }

    // Phase 2: 150 dot-32s per thread against wave-uniform (s_load) q rows.
    // unroll 2: next q-row s_load pipelines under current row's FMAs.
    const float* __restrict__ qb =
        ws + ((size_t)b * N_PER + g * NHALF) * KEY_DIM;
    float* __restrict__ ob =
        out + ((size_t)b * N_PER + (size_t)g * NHALF) * HW + pix;

    #pragma unroll 2
    for (int n = 0; n < NHALF; ++n) {
        const float* __restrict__ qn = qb + n * KEY_DIM;
        float a0 = 0.f, a1 = 0.f, a2 = 0.f, a3 = 0.f;
        #pragma unroll
        for (int c2 = 0; c2 < KEY_DIM; c2 += 4) {
            a0 += qn[c2 + 0] * key[c2 + 0];
            a1 += qn[c2 + 1] * key[c2 + 1];
            a2 += qn[c2 + 2] * key[c2 + 2];
            a3 += qn[c2 + 3] * key[c2 + 3];
        }
        ob[(size_t)n * HW] = (a0 + a1) + (a2 + a3);
    }
}

extern "C" void kernel_launch(void* const* d_in, const int* in_sizes, int n_in,
                              void* d_out, int out_size, void* d_ws, size_t ws_size,
                              hipStream_t stream) {
    const float* in_feats = (const float*)d_in[0];  // [1200, 256]
    const float* feat_map = (const float*)d_in[1];  // [4, 256, 160, 160]
    const float* qry_w    = (const float*)d_in[2];  // [32, 256]
    const float* qry_b    = (const float*)d_in[3];  // [32]
    const float* key_w    = (const float*)d_in[4];  // [32, 256]
    const float* key_b    = (const float*)d_in[5];  // [32]
    float* ws  = (float*)d_ws;                      // needs 46592*4 B
    float* out = (float*)d_out;                     // [1200, 160, 160] fp32

    // Prep: 1200 q-blocks + 32 transpose blocks.
    prep_kernel<<<dim3(QBLOCKS + TBLOCKS), dim3(256), 0, stream>>>(
        in_feats, qry_w, qry_b, key_w, ws);

    // Main: 100 pixel-tiles x 4 batches, 512 threads each (6400 waves).
    main_kernel<<<dim3(HW / 256, BATCH), dim3(512), 0, stream>>>(
        feat_map, key_b, ws, out);
}